// Round 15
// baseline (258.482 us; speedup 1.0000x reference)
//
#include <hip/hip_runtime.h>
#include <hip/hip_bf16.h>
#include <stdint.h>

typedef __hip_bfloat16 bf16;
typedef __attribute__((ext_vector_type(8))) short short8;
typedef __attribute__((ext_vector_type(4))) float f32x4;

#define NTOK  4096      // B*T
#define EDIM  1024
#define NEXPT 8
#define INTERD 1408
#define MAXP  4096
#define WELEM (NEXPT * INTERD * EDIM)

// async global->LDS, 16B per lane, dest = wave-uniform base + lane*16 (LINEAR)
#define GL16(g, l) __builtin_amdgcn_global_load_lds( \
    (const __attribute__((address_space(1))) unsigned int*)(g), \
    (__attribute__((address_space(3))) unsigned int*)(l), 16, 0, 0)

#define WAIT_VM(n)   asm volatile("s_waitcnt vmcnt(" #n ")" ::: "memory")
#define BAR()        __builtin_amdgcn_s_barrier()
#define PRIO(n)      __builtin_amdgcn_s_setprio(n)

// ---- prep: fused {wg,wu,wd -> bf16} + {router top2 + probs + x->bf16}. NO ATOMICS. --
__global__ __launch_bounds__(256) void prep_kernel(const float* __restrict__ wg, bf16* __restrict__ wgb,
                                                   const float* __restrict__ wu, bf16* __restrict__ wub,
                                                   const float* __restrict__ wd, bf16* __restrict__ wdb,
                                                   const float* __restrict__ x,
                                                   const float* __restrict__ gw,
                                                   bf16* __restrict__ xb,
                                                   int* __restrict__ sel,
                                                   float* __restrict__ tprob) {
    int b = blockIdx.x;
    if (b < 3072) {
        const float* src; bf16* dst;
        if (b < 1024)      { src = wg; dst = wgb; }
        else if (b < 2048) { src = wu; dst = wub; b -= 1024; }
        else               { src = wd; dst = wdb; b -= 2048; }
        int i = (b * 256 + threadIdx.x) * 4;
        int stride = 1024 * 256 * 4;
        for (; i < WELEM; i += stride) {
            float4 v = *(const float4*)(src + i);
            ushort4 o; bf16 t;
            t = __float2bfloat16(v.x); o.x = *(unsigned short*)&t;
            t = __float2bfloat16(v.y); o.y = *(unsigned short*)&t;
            t = __float2bfloat16(v.z); o.z = *(unsigned short*)&t;
            t = __float2bfloat16(v.w); o.w = *(unsigned short*)&t;
            *(ushort4*)(dst + i) = o;
        }
        return;
    }
    // ---- router: one token per wave, fp64-exact scores ----
    int t = (b - 3072) * 4 + (threadIdx.x >> 6);
    int lane = threadIdx.x & 63;
    const float* xr = x + (size_t)t * EDIM;
    float xv[16];
#pragma unroll
    for (int j = 0; j < 4; j++) {
        float4 v = *(const float4*)(xr + lane * 16 + j * 4);
        xv[4 * j] = v.x; xv[4 * j + 1] = v.y; xv[4 * j + 2] = v.z; xv[4 * j + 3] = v.w;
    }
    bf16* xbr = xb + (size_t)t * EDIM;
#pragma unroll
    for (int j = 0; j < 4; j++) {
        ushort4 o; bf16 c;
        c = __float2bfloat16(xv[4 * j]);     o.x = *(unsigned short*)&c;
        c = __float2bfloat16(xv[4 * j + 1]); o.y = *(unsigned short*)&c;
        c = __float2bfloat16(xv[4 * j + 2]); o.z = *(unsigned short*)&c;
        c = __float2bfloat16(xv[4 * j + 3]); o.w = *(unsigned short*)&c;
        *(ushort4*)(xbr + lane * 16 + j * 4) = o;
    }
    double acc[NEXPT];
#pragma unroll
    for (int e = 0; e < NEXPT; e++) acc[e] = 0.0;
#pragma unroll
    for (int e = 0; e < NEXPT; e++) {
        const float* gr = gw + e * EDIM + lane * 16;
#pragma unroll
        for (int j = 0; j < 16; j++) acc[e] += (double)xv[j] * (double)gr[j];
    }
#pragma unroll
    for (int off = 32; off >= 1; off >>= 1) {
#pragma unroll
        for (int e = 0; e < NEXPT; e++) acc[e] += __shfl_xor(acc[e], off, 64);
    }
    if (lane == 0) {
        int e0 = 0; double s0 = acc[0];
        for (int e = 1; e < NEXPT; e++) if (acc[e] > s0) { s0 = acc[e]; e0 = e; }
        int e1 = -1; double s1 = -1e300;
        for (int e = 0; e < NEXPT; e++) if (e != e0 && acc[e] > s1) { s1 = acc[e]; e1 = e; }
        float z = __expf((float)(s1 - s0));
        float p0 = 1.f / (1.f + z);
        sel[t] = e0 | (e1 << 8);
        tprob[2 * t] = p0;
        tprob[2 * t + 1] = 1.f - p0;
    }
}

// ------- bucket: stable counting-sort of (token,slot) into expert buckets ----------
__global__ __launch_bounds__(512) void bucket_kernel(const int* __restrict__ sel,
                                                     const float* __restrict__ tprob,
                                                     int* __restrict__ counts,
                                                     int* __restrict__ offsets,
                                                     int* __restrict__ ptok,
                                                     float* __restrict__ pprob,
                                                     int* __restrict__ inv,
                                                     int* __restrict__ wq1,
                                                     int* __restrict__ wq2) {
    __shared__ int scnt[NEXPT];
    int w = threadIdx.x >> 6;
    int lane = threadIdx.x & 63;
    unsigned long long ltmask = (lane == 63) ? ~0ull >> 1 : (1ull << lane) - 1;
    int base = 0;
    for (int t0 = 0; t0 < NTOK; t0 += 64) {
        int t = t0 + lane;
        int s = sel[t];
        int e0 = s & 0xff, e1 = (s >> 8) & 0xff;
        unsigned long long m0 = __ballot(e0 == w);
        if (e0 == w) {
            int pos = base + __popcll(m0 & ltmask);
            ptok[w * MAXP + pos] = t;
            pprob[w * MAXP + pos] = tprob[2 * t];
            inv[2 * t] = (w << 16) | pos;
        }
        base += __popcll(m0);
        unsigned long long m1 = __ballot(e1 == w);
        if (e1 == w) {
            int pos = base + __popcll(m1 & ltmask);
            ptok[w * MAXP + pos] = t;
            pprob[w * MAXP + pos] = tprob[2 * t + 1];
            inv[2 * t + 1] = (w << 16) | pos;
        }
        base += __popcll(m1);
    }
    if (lane == 0) scnt[w] = base;
    __syncthreads();
    if (threadIdx.x < NEXPT) {
        int off = 0;
        for (int e = 0; e < (int)threadIdx.x; e++) off += scnt[e];
        counts[threadIdx.x] = scnt[threadIdx.x];
        offsets[threadIdx.x] = off;
        wq1[threadIdx.x * 32] = 0;    // 128B-padded queue heads
        wq2[threadIdx.x * 32] = 0;
    }
}

// ======================= GEMM1: h = p * silu(x@wg^T) * (x@wu^T) =======================
// Tile 128tok x 128inter, BK=32, 32 K-tiles. 8 waves (2M x 4N), wave 64x32 on g AND u.
// 3-slot LDS ring (72KB) -> 2 blocks/CU. Prefetch 2, counted vmcnt(6), XOR swizzle.
// (512,4): no spills. Padded per-expert queue + stealing; bx&7 = expert -> XCD.
__global__ __launch_bounds__(512, 4) void gemm1_kernel(const bf16* __restrict__ xb,
                                                       const bf16* __restrict__ wgb,
                                                       const bf16* __restrict__ wub,
                                                       bf16* __restrict__ hout,
                                                       const int* __restrict__ counts,
                                                       const int* __restrict__ offsets,
                                                       const int* __restrict__ ptok,
                                                       const float* __restrict__ pprob,
                                                       int* __restrict__ wq1) {
    int eown = blockIdx.x & 7;

    __shared__ __align__(16) bf16 smem[3 * 12288];
    __shared__ int s_wi;

    int tid  = threadIdx.x;
    int lane = tid & 63;
    int wid  = tid >> 6;
    int wm   = wid >> 2;              // 0..1  (64-tok stripe)
    int wn   = wid & 3;               // 0..3  (32-inter stripe)

    int srow = tid >> 2;                              // staging row 0..127
    int qs   = (((tid & 3) ^ ((srow >> 1) & 3)) * 8); // swizzled SOURCE chunk (elems)
    int l15  = lane & 15;
    int l4   = lane >> 4;                             // 0..3 (K-chunk)

    int offA[4], offG[2];
#pragma unroll
    for (int m = 0; m < 4; m++) {
        int r = wm * 64 + m * 16 + l15;
        offA[m] = r * 32 + ((l4 ^ ((r >> 1) & 3)) * 8);
    }
#pragma unroll
    for (int n = 0; n < 2; n++) {
        int r = wn * 32 + n * 16 + l15;
        offG[n] = r * 32 + ((l4 ^ ((r >> 1) & 3)) * 8);
    }

    for (int ei = 0; ei < NEXPT; ++ei) {
        int e = (eown + ei) & 7;      // own expert first, then steal
        int cnt = counts[e];
        int mtiles = (cnt + 127) >> 7;
        int tiles = mtiles * (INTERD / 128);
        int hbase = offsets[e];

        for (;;) {
            if (tid == 0) s_wi = atomicAdd(&wq1[e * 32], 1);
            __syncthreads();
            int wi = s_wi;
            __syncthreads();
            if (wi >= tiles) break;
            int mt = wi % mtiles;     // mt-fastest: concurrent blocks share G/U panel
            int nt = wi / mtiles;
            int m0 = mt * 128;
            int n0 = nt * 128;

            WAIT_VM(0);               // clean vmcnt (prior stores drained)
            const bf16* gA = xb + (size_t)ptok[e * MAXP + min(m0 + srow, cnt - 1)] * EDIM + qs;
            const bf16* gG = wgb + ((size_t)e * INTERD + n0 + srow) * EDIM + qs;
            const bf16* gU = wub + ((size_t)e * INTERD + n0 + srow) * EDIM + qs;

            f32x4 accg[4][2], accu[4][2];
#pragma unroll
            for (int m = 0; m < 4; m++)
#pragma unroll
                for (int n = 0; n < 2; n++) {
                    accg[m][n] = (f32x4){0.f, 0.f, 0.f, 0.f};
                    accu[m][n] = (f32x4){0.f, 0.f, 0.f, 0.f};
                }

#define SB1(t) (smem + ((t) % 3) * 12288)
#define G1_STAGE(t) do { bf16* sb_ = SB1(t); int ko_ = (t) * 32; \
            GL16(gA + ko_, sb_ + wid * 512); \
            GL16(gG + ko_, sb_ + 4096 + wid * 512); \
            GL16(gU + ko_, sb_ + 8192 + wid * 512); } while (0)

            G1_STAGE(0); G1_STAGE(1);     // 6 loads in flight

            for (int t = 0; t < 32; ++t) {
                if (t < 30)       { G1_STAGE(t + 2); WAIT_VM(6); }  // tile t landed
                else if (t == 30) { WAIT_VM(3); }
                else              { WAIT_VM(0); }
                BAR();
                const bf16* sb = SB1(t);
                short8 a_[4], gf[2], uf[2];
#pragma unroll
                for (int m = 0; m < 4; m++) a_[m] = *(const short8*)&sb[offA[m]];
#pragma unroll
                for (int n = 0; n < 2; n++) {
                    gf[n] = *(const short8*)&sb[4096 + offG[n]];
                    uf[n] = *(const short8*)&sb[8192 + offG[n]];
                }
                PRIO(1);
#pragma unroll
                for (int m = 0; m < 4; m++)
#pragma unroll
                    for (int n = 0; n < 2; n++) {
                        accg[m][n] = __builtin_amdgcn_mfma_f32_16x16x32_bf16(a_[m], gf[n], accg[m][n], 0, 0, 0);
                        accu[m][n] = __builtin_amdgcn_mfma_f32_16x16x32_bf16(a_[m], uf[n], accu[m][n], 0, 0, 0);
                    }
                PRIO(0);
                BAR();
            }
#undef SB1
#undef G1_STAGE

            // epilogue: h = silu(g) * u * p
#pragma unroll
            for (int m = 0; m < 4; m++)
#pragma unroll
                for (int n = 0; n < 2; n++)
#pragma unroll
                    for (int r = 0; r < 4; r++) {
                        int pos = m0 + wm * 64 + m * 16 + l4 * 4 + r;
                        if (pos < cnt) {
                            int col = n0 + wn * 32 + n * 16 + l15;
                            float p = pprob[e * MAXP + pos];
                            float gv = accg[m][n][r];
                            float uv = accu[m][n][r];
                            float hv = (gv / (1.f + __expf(-gv))) * uv * p;
                            hout[(size_t)(hbase + pos) * INTERD + col] = __float2bfloat16(hv);
                        }
                    }
        }
    }
}

// ======================= GEMM2: out2[slot] = h[slot] @ wd[e]^T (bf16) =================
// K-SPLIT: tile 128slot x 128col, 8 waves = 2M x 2N x 2K; wave-tile 64x64 over half-K.
// Per step: stage A[128][64]+B[128][64] (32KB), wave reads its K-half (8 ds_read_b128
// -> 16 MFMA per barrier pair). 2-slot ring 64KB -> 2 blocks/CU (16 waves). Prefetch 1,
// counted vmcnt(4). 3-bit XOR swizzle. Epilogue: wk=1 waves spill acc to smem (XOR'd),
// wk=0 waves add + store bf16. ~512 tiles over 512 blocks -> single round. (512,4).
__global__ __launch_bounds__(512, 4) void gemm2_kernel(const bf16* __restrict__ h,
                                                       const bf16* __restrict__ wdb,
                                                       bf16* __restrict__ out2,
                                                       const int* __restrict__ counts,
                                                       const int* __restrict__ offsets,
                                                       int* __restrict__ wq2) {
    int eown = blockIdx.x & 7;

    __shared__ __align__(16) bf16 smem[2 * 16384];   // 64KB ring; reused as 16384-float reduce buf
    __shared__ int s_wi;

    int tid  = threadIdx.x;
    int lane = tid & 63;
    int wid  = tid >> 6;              // 0..7
    int pair = wid & 3;
    int wm   = pair >> 1;             // 0..1 (64-slot stripe)
    int wn   = pair & 1;              // 0..1 (64-col stripe)
    int wk   = wid >> 2;              // 0..1 (K-half)

    int srow = tid >> 3;                              // staging row 0..63 (128B rows)
    int qs   = (((tid & 7) ^ (srow & 7)) * 8);        // swizzled SOURCE chunk (elems)
    int l15  = lane & 15;
    int l4   = lane >> 4;

    // swizzled LDS read offsets: K-chunk c = wk*4 + l4 within 64-elem row
    int offA[4], offB[4];
#pragma unroll
    for (int m = 0; m < 4; m++) {
        int r = wm * 64 + m * 16 + l15;
        offA[m] = r * 64 + (((wk * 4 + l4) ^ (r & 7)) * 8);
    }
#pragma unroll
    for (int n = 0; n < 4; n++) {
        int r = wn * 64 + n * 16 + l15;
        offB[n] = 8192 + r * 64 + (((wk * 4 + l4) ^ (r & 7)) * 8);
    }

    for (int ei = 0; ei < NEXPT; ++ei) {
        int e = (eown + ei) & 7;
        int cnt = counts[e];
        int mtiles = (cnt + 127) >> 7;
        int tiles = mtiles * (EDIM / 128);
        int hbase = offsets[e];

        for (;;) {
            if (tid == 0) s_wi = atomicAdd(&wq2[e * 32], 1);
            __syncthreads();
            int wi = s_wi;
            __syncthreads();
            if (wi >= tiles) break;
            int mt = wi % mtiles;     // mt-fastest: concurrent blocks share wd panel
            int nt = wi / mtiles;
            int m0 = mt * 128;
            int n0 = nt * 128;

            WAIT_VM(0);               // prior epilogue stores drained
            const bf16* gA0 = h + (size_t)(hbase + min(m0 + srow,      cnt - 1)) * INTERD + qs;
            const bf16* gA1 = h + (size_t)(hbase + min(m0 + 64 + srow, cnt - 1)) * INTERD + qs;
            const bf16* gB0 = wdb + ((size_t)e * EDIM + n0 + srow) * INTERD + qs;
            const bf16* gB1 = wdb + ((size_t)e * EDIM + n0 + 64 + srow) * INTERD + qs;

            f32x4 acc[4][4];
#pragma unroll
            for (int m = 0; m < 4; m++)
#pragma unroll
                for (int n = 0; n < 4; n++) acc[m][n] = (f32x4){0.f, 0.f, 0.f, 0.f};

#define SB2(t) (smem + ((t) & 1) * 16384)
#define G2_STAGE(t) do { bf16* sb_ = SB2(t); int ko_ = (t) * 64; \
            GL16(gA0 + ko_, sb_ + wid * 512); \
            GL16(gA1 + ko_, sb_ + 4096 + wid * 512); \
            GL16(gB0 + ko_, sb_ + 8192 + wid * 512); \
            GL16(gB1 + ko_, sb_ + 12288 + wid * 512); } while (0)

            G2_STAGE(0);              // 4 loads in flight

            for (int t = 0; t < 22; ++t) {
                if (t < 21) { G2_STAGE(t + 1); WAIT_VM(4); }   // tile t landed
                else        { WAIT_VM(0); }
                BAR();
                const bf16* sb = SB2(t);
                short8 a_[4], b_[4];
#pragma unroll
                for (int m = 0; m < 4; m++) a_[m] = *(const short8*)&sb[offA[m]];
#pragma unroll
                for (int n = 0; n < 4; n++) b_[n] = *(const short8*)&sb[offB[n]];
                PRIO(1);
#pragma unroll
                for (int m = 0; m < 4; m++)
#pragma unroll
                    for (int n = 0; n < 4; n++)
                        acc[m][n] = __builtin_amdgcn_mfma_f32_16x16x32_bf16(a_[m], b_[n], acc[m][n], 0, 0, 0);
                PRIO(0);
                BAR();
            }
#undef SB2
#undef G2_STAGE

            // ---- K-half reduction: wk=1 spills acc to smem, wk=0 adds + stores ----
            float* fbuf = (float*)smem;   // 16384 floats = 64KB, exactly 4 pairs x 64 lanes x 64
            if (wk == 1) {
#pragma unroll
                for (int m = 0; m < 4; m++)
#pragma unroll
                    for (int n = 0; n < 4; n++) {
                        int i = (m * 4 + n) * 4;
                        int a = pair * 4096 + lane * 64 + (i ^ ((lane & 15) << 2));
                        *(f32x4*)&fbuf[a] = acc[m][n];
                    }
            }
            __syncthreads();
            if (wk == 0) {
#pragma unroll
                for (int m = 0; m < 4; m++)
#pragma unroll
                    for (int n = 0; n < 4; n++) {
                        int i = (m * 4 + n) * 4;
                        int a = pair * 4096 + lane * 64 + (i ^ ((lane & 15) << 2));
                        f32x4 v = *(const f32x4*)&fbuf[a];
                        acc[m][n][0] += v[0]; acc[m][n][1] += v[1];
                        acc[m][n][2] += v[2]; acc[m][n][3] += v[3];
                    }
#pragma unroll
                for (int m = 0; m < 4; m++)
#pragma unroll
                    for (int n = 0; n < 4; n++)
#pragma unroll
                        for (int r = 0; r < 4; r++) {
                            int pos = m0 + wm * 64 + m * 16 + l4 * 4 + r;
                            if (pos < cnt) {
                                int col = n0 + wn * 64 + n * 16 + l15;
                                out2[(size_t)(hbase + pos) * EDIM + col] = __float2bfloat16(acc[m][n][r]);
                            }
                        }
            }
            __syncthreads();          // fbuf reads done before next tile's staging
        }
    }
}

// ---------------- combine: y[t] = out2[slot0] + out2[slot1] (probs already folded) ---
__global__ __launch_bounds__(256) void combine_kernel(const bf16* __restrict__ out2,
                                                      const int* __restrict__ inv,
                                                      const int* __restrict__ offsets,
                                                      float* __restrict__ y) {
    int idx = blockIdx.x * 256 + threadIdx.x;   // NTOK*EDIM/8 threads
    int t = idx >> 7;
    int c = (idx & 127) * 8;
    int a = inv[2 * t], b = inv[2 * t + 1];
    const short8 va = *(const short8*)(out2 + (size_t)(offsets[a >> 16] + (a & 0xFFFF)) * EDIM + c);
    const short8 vb = *(const short8*)(out2 + (size_t)(offsets[b >> 16] + (b & 0xFFFF)) * EDIM + c);
    float o[8];
#pragma unroll
    for (int j = 0; j < 8; j++) {
        unsigned ua = ((unsigned)(unsigned short)va[j]) << 16;
        unsigned ub = ((unsigned)(unsigned short)vb[j]) << 16;
        o[j] = *(float*)&ua + *(float*)&ub;
    }
    float* yp = y + (size_t)t * EDIM + c;
    *(float4*)yp       = (float4){o[0], o[1], o[2], o[3]};
    *(float4*)(yp + 4) = (float4){o[4], o[5], o[6], o[7]};
}

// ---------------- launch ----------------
extern "C" void kernel_launch(void* const* d_in, const int* in_sizes, int n_in,
                              void* d_out, int out_size, void* d_ws, size_t ws_size,
                              hipStream_t stream) {
    const float* x      = (const float*)d_in[0];
    const float* gate_w = (const float*)d_in[1];
    const float* wg     = (const float*)d_in[2];
    const float* wu     = (const float*)d_in[3];
    const float* wd     = (const float*)d_in[4];
    float* y = (float*)d_out;

    char* ws = (char*)d_ws;
    constexpr size_t SZ_XB = (size_t)NTOK * EDIM * 2;          // 8 MB
    constexpr size_t SZ_W  = (size_t)WELEM * 2;                // 23.07 MB
    constexpr size_t SZ_H  = (size_t)NTOK * 2 * INTERD * 2;    // 23.07 MB
    bf16* xb  = (bf16*)ws;
    bf16* wgb = (bf16*)(ws + SZ_XB);
    bf16* wub = (bf16*)(ws + SZ_XB + SZ_W);
    bf16* wdb = (bf16*)(ws + SZ_XB + 2 * SZ_W);
    bf16* h   = (bf16*)(ws + SZ_XB + 3 * SZ_W);
    char* meta = ws + SZ_XB + 3 * SZ_W + SZ_H;
    int*   counts  = (int*)meta;
    int*   offsets = (int*)(meta + 256);
    int*   ptok    = (int*)(meta + 512);
    float* pprob   = (float*)(meta + 512 + (size_t)NEXPT * MAXP * 4);
    int*   inv     = (int*)(meta + 512 + (size_t)NEXPT * MAXP * 8);
    char*  meta2   = meta + 512 + (size_t)NEXPT * MAXP * 8 + (size_t)NTOK * 2 * 4;
    int*   wq1     = (int*)meta2;                      // 8 entries, 128B stride
    int*   wq2     = (int*)(meta2 + 1024);             // 8 entries, 128B stride
    int*   sel     = (int*)(meta2 + 2048);
    float* tprob   = (float*)(meta2 + 2048 + (size_t)NTOK * 4);
    // out2 bf16 (8192*1024*2 = 16.8 MB) aliases wgb (23 MB), dead after gemm1
    bf16* out2 = (bf16*)(ws + SZ_XB);

    prep_kernel<<<3072 + NTOK / 4, 256, 0, stream>>>(wg, wgb, wu, wub, wd, wdb,
                                                     x, gate_w, xb, sel, tprob);
    bucket_kernel<<<1, 512, 0, stream>>>(sel, tprob, counts, offsets, ptok, pprob, inv,
                                         wq1, wq2);

    // 512 blocks (2/CU, 72KB LDS); per-expert queue + steal; bx&7 = expert -> XCD
    gemm1_kernel<<<512, 512, 0, stream>>>(
        xb, wgb, wub, h, counts, offsets, ptok, pprob, wq1);
    // 512 blocks (2/CU, 64KB LDS); K-split 8-wave; ~512 tiles -> single round
    gemm2_kernel<<<512, 512, 0, stream>>>(
        h, wdb, out2, counts, offsets, wq2);
    combine_kernel<<<NTOK * EDIM / 8 / 256, 256, 0, stream>>>(out2, inv, offsets, y);
}

// Round 16
// 219.401 us; speedup vs baseline: 1.1781x; 1.1781x over previous
//
#include <hip/hip_runtime.h>
#include <hip/hip_bf16.h>
#include <stdint.h>

typedef __hip_bfloat16 bf16;
typedef __attribute__((ext_vector_type(8))) short short8;
typedef __attribute__((ext_vector_type(4))) float f32x4;

#define NTOK  4096      // B*T
#define EDIM  1024
#define NEXPT 8
#define INTERD 1408
#define MAXP  4096
#define WELEM (NEXPT * INTERD * EDIM)

// async global->LDS, 16B per lane, dest = wave-uniform base + lane*16 (LINEAR)
#define GL16(g, l) __builtin_amdgcn_global_load_lds( \
    (const __attribute__((address_space(1))) unsigned int*)(g), \
    (__attribute__((address_space(3))) unsigned int*)(l), 16, 0, 0)

#define WAIT_VM(n)   asm volatile("s_waitcnt vmcnt(" #n ")" ::: "memory")
#define BAR()        __builtin_amdgcn_s_barrier()
#define PRIO(n)      __builtin_amdgcn_s_setprio(n)

// ---- prep: fused {wg,wu,wd -> bf16} + {router top2 + probs + x->bf16}. NO ATOMICS. --
__global__ __launch_bounds__(256) void prep_kernel(const float* __restrict__ wg, bf16* __restrict__ wgb,
                                                   const float* __restrict__ wu, bf16* __restrict__ wub,
                                                   const float* __restrict__ wd, bf16* __restrict__ wdb,
                                                   const float* __restrict__ x,
                                                   const float* __restrict__ gw,
                                                   bf16* __restrict__ xb,
                                                   int* __restrict__ sel,
                                                   float* __restrict__ tprob) {
    int b = blockIdx.x;
    if (b < 3072) {
        const float* src; bf16* dst;
        if (b < 1024)      { src = wg; dst = wgb; }
        else if (b < 2048) { src = wu; dst = wub; b -= 1024; }
        else               { src = wd; dst = wdb; b -= 2048; }
        int i = (b * 256 + threadIdx.x) * 4;
        int stride = 1024 * 256 * 4;
        for (; i < WELEM; i += stride) {
            float4 v = *(const float4*)(src + i);
            ushort4 o; bf16 t;
            t = __float2bfloat16(v.x); o.x = *(unsigned short*)&t;
            t = __float2bfloat16(v.y); o.y = *(unsigned short*)&t;
            t = __float2bfloat16(v.z); o.z = *(unsigned short*)&t;
            t = __float2bfloat16(v.w); o.w = *(unsigned short*)&t;
            *(ushort4*)(dst + i) = o;
        }
        return;
    }
    // ---- router: one token per wave, fp64-exact scores ----
    int t = (b - 3072) * 4 + (threadIdx.x >> 6);
    int lane = threadIdx.x & 63;
    const float* xr = x + (size_t)t * EDIM;
    float xv[16];
#pragma unroll
    for (int j = 0; j < 4; j++) {
        float4 v = *(const float4*)(xr + lane * 16 + j * 4);
        xv[4 * j] = v.x; xv[4 * j + 1] = v.y; xv[4 * j + 2] = v.z; xv[4 * j + 3] = v.w;
    }
    bf16* xbr = xb + (size_t)t * EDIM;
#pragma unroll
    for (int j = 0; j < 4; j++) {
        ushort4 o; bf16 c;
        c = __float2bfloat16(xv[4 * j]);     o.x = *(unsigned short*)&c;
        c = __float2bfloat16(xv[4 * j + 1]); o.y = *(unsigned short*)&c;
        c = __float2bfloat16(xv[4 * j + 2]); o.z = *(unsigned short*)&c;
        c = __float2bfloat16(xv[4 * j + 3]); o.w = *(unsigned short*)&c;
        *(ushort4*)(xbr + lane * 16 + j * 4) = o;
    }
    double acc[NEXPT];
#pragma unroll
    for (int e = 0; e < NEXPT; e++) acc[e] = 0.0;
#pragma unroll
    for (int e = 0; e < NEXPT; e++) {
        const float* gr = gw + e * EDIM + lane * 16;
#pragma unroll
        for (int j = 0; j < 16; j++) acc[e] += (double)xv[j] * (double)gr[j];
    }
#pragma unroll
    for (int off = 32; off >= 1; off >>= 1) {
#pragma unroll
        for (int e = 0; e < NEXPT; e++) acc[e] += __shfl_xor(acc[e], off, 64);
    }
    if (lane == 0) {
        int e0 = 0; double s0 = acc[0];
        for (int e = 1; e < NEXPT; e++) if (acc[e] > s0) { s0 = acc[e]; e0 = e; }
        int e1 = -1; double s1 = -1e300;
        for (int e = 0; e < NEXPT; e++) if (e != e0 && acc[e] > s1) { s1 = acc[e]; e1 = e; }
        float z = __expf((float)(s1 - s0));
        float p0 = 1.f / (1.f + z);
        sel[t] = e0 | (e1 << 8);
        tprob[2 * t] = p0;
        tprob[2 * t + 1] = 1.f - p0;
    }
}

// ------- bucket: stable counting-sort of (token,slot) into expert buckets ----------
__global__ __launch_bounds__(512) void bucket_kernel(const int* __restrict__ sel,
                                                     const float* __restrict__ tprob,
                                                     int* __restrict__ counts,
                                                     int* __restrict__ offsets,
                                                     int* __restrict__ ptok,
                                                     float* __restrict__ pprob,
                                                     int* __restrict__ inv,
                                                     int* __restrict__ wq1,
                                                     int* __restrict__ wq2) {
    __shared__ int scnt[NEXPT];
    int w = threadIdx.x >> 6;
    int lane = threadIdx.x & 63;
    unsigned long long ltmask = (lane == 63) ? ~0ull >> 1 : (1ull << lane) - 1;
    int base = 0;
    for (int t0 = 0; t0 < NTOK; t0 += 64) {
        int t = t0 + lane;
        int s = sel[t];
        int e0 = s & 0xff, e1 = (s >> 8) & 0xff;
        unsigned long long m0 = __ballot(e0 == w);
        if (e0 == w) {
            int pos = base + __popcll(m0 & ltmask);
            ptok[w * MAXP + pos] = t;
            pprob[w * MAXP + pos] = tprob[2 * t];
            inv[2 * t] = (w << 16) | pos;
        }
        base += __popcll(m0);
        unsigned long long m1 = __ballot(e1 == w);
        if (e1 == w) {
            int pos = base + __popcll(m1 & ltmask);
            ptok[w * MAXP + pos] = t;
            pprob[w * MAXP + pos] = tprob[2 * t + 1];
            inv[2 * t + 1] = (w << 16) | pos;
        }
        base += __popcll(m1);
    }
    if (lane == 0) scnt[w] = base;
    __syncthreads();
    if (threadIdx.x < NEXPT) {
        int off = 0;
        for (int e = 0; e < (int)threadIdx.x; e++) off += scnt[e];
        counts[threadIdx.x] = scnt[threadIdx.x];
        offsets[threadIdx.x] = off;
        wq1[threadIdx.x * 32] = 0;    // 128B-padded queue heads
        wq2[threadIdx.x * 32] = 0;
    }
}

// ======================= GEMM1: h = p * silu(x@wg^T) * (x@wu^T) =======================
// Tile 128tok x 128inter, BK=32, 32 K-tiles. 8 waves (2M x 4N), wave 64x32 on g AND u.
// 3-slot LDS ring (72KB) -> 2 blocks/CU. Prefetch 2, counted vmcnt(6), XOR swizzle.
// (512,4): no spills. Padded per-expert queue + stealing; bx&7 = expert -> XCD.
__global__ __launch_bounds__(512, 4) void gemm1_kernel(const bf16* __restrict__ xb,
                                                       const bf16* __restrict__ wgb,
                                                       const bf16* __restrict__ wub,
                                                       bf16* __restrict__ hout,
                                                       const int* __restrict__ counts,
                                                       const int* __restrict__ offsets,
                                                       const int* __restrict__ ptok,
                                                       const float* __restrict__ pprob,
                                                       int* __restrict__ wq1) {
    int eown = blockIdx.x & 7;

    __shared__ __align__(16) bf16 smem[3 * 12288];
    __shared__ int s_wi;

    int tid  = threadIdx.x;
    int lane = tid & 63;
    int wid  = tid >> 6;
    int wm   = wid >> 2;              // 0..1  (64-tok stripe)
    int wn   = wid & 3;               // 0..3  (32-inter stripe)

    int srow = tid >> 2;                              // staging row 0..127
    int qs   = (((tid & 3) ^ ((srow >> 1) & 3)) * 8); // swizzled SOURCE chunk (elems)
    int l15  = lane & 15;
    int l4   = lane >> 4;                             // 0..3 (K-chunk)

    int offA[4], offG[2];
#pragma unroll
    for (int m = 0; m < 4; m++) {
        int r = wm * 64 + m * 16 + l15;
        offA[m] = r * 32 + ((l4 ^ ((r >> 1) & 3)) * 8);
    }
#pragma unroll
    for (int n = 0; n < 2; n++) {
        int r = wn * 32 + n * 16 + l15;
        offG[n] = r * 32 + ((l4 ^ ((r >> 1) & 3)) * 8);
    }

    for (int ei = 0; ei < NEXPT; ++ei) {
        int e = (eown + ei) & 7;      // own expert first, then steal
        int cnt = counts[e];
        int mtiles = (cnt + 127) >> 7;
        int tiles = mtiles * (INTERD / 128);
        int hbase = offsets[e];

        for (;;) {
            if (tid == 0) s_wi = atomicAdd(&wq1[e * 32], 1);
            __syncthreads();
            int wi = s_wi;
            __syncthreads();
            if (wi >= tiles) break;
            int mt = wi % mtiles;     // mt-fastest: concurrent blocks share G/U panel
            int nt = wi / mtiles;
            int m0 = mt * 128;
            int n0 = nt * 128;

            WAIT_VM(0);               // clean vmcnt (prior stores drained)
            const bf16* gA = xb + (size_t)ptok[e * MAXP + min(m0 + srow, cnt - 1)] * EDIM + qs;
            const bf16* gG = wgb + ((size_t)e * INTERD + n0 + srow) * EDIM + qs;
            const bf16* gU = wub + ((size_t)e * INTERD + n0 + srow) * EDIM + qs;

            f32x4 accg[4][2], accu[4][2];
#pragma unroll
            for (int m = 0; m < 4; m++)
#pragma unroll
                for (int n = 0; n < 2; n++) {
                    accg[m][n] = (f32x4){0.f, 0.f, 0.f, 0.f};
                    accu[m][n] = (f32x4){0.f, 0.f, 0.f, 0.f};
                }

#define SB1(t) (smem + ((t) % 3) * 12288)
#define G1_STAGE(t) do { bf16* sb_ = SB1(t); int ko_ = (t) * 32; \
            GL16(gA + ko_, sb_ + wid * 512); \
            GL16(gG + ko_, sb_ + 4096 + wid * 512); \
            GL16(gU + ko_, sb_ + 8192 + wid * 512); } while (0)

            G1_STAGE(0); G1_STAGE(1);     // 6 loads in flight

            for (int t = 0; t < 32; ++t) {
                if (t < 30)       { G1_STAGE(t + 2); WAIT_VM(6); }  // tile t landed
                else if (t == 30) { WAIT_VM(3); }
                else              { WAIT_VM(0); }
                BAR();
                const bf16* sb = SB1(t);
                short8 a_[4], gf[2], uf[2];
#pragma unroll
                for (int m = 0; m < 4; m++) a_[m] = *(const short8*)&sb[offA[m]];
#pragma unroll
                for (int n = 0; n < 2; n++) {
                    gf[n] = *(const short8*)&sb[4096 + offG[n]];
                    uf[n] = *(const short8*)&sb[8192 + offG[n]];
                }
                PRIO(1);
#pragma unroll
                for (int m = 0; m < 4; m++)
#pragma unroll
                    for (int n = 0; n < 2; n++) {
                        accg[m][n] = __builtin_amdgcn_mfma_f32_16x16x32_bf16(a_[m], gf[n], accg[m][n], 0, 0, 0);
                        accu[m][n] = __builtin_amdgcn_mfma_f32_16x16x32_bf16(a_[m], uf[n], accu[m][n], 0, 0, 0);
                    }
                PRIO(0);
                BAR();
            }
#undef SB1
#undef G1_STAGE

            // epilogue: h = silu(g) * u * p
#pragma unroll
            for (int m = 0; m < 4; m++)
#pragma unroll
                for (int n = 0; n < 2; n++)
#pragma unroll
                    for (int r = 0; r < 4; r++) {
                        int pos = m0 + wm * 64 + m * 16 + l4 * 4 + r;
                        if (pos < cnt) {
                            int col = n0 + wn * 32 + n * 16 + l15;
                            float p = pprob[e * MAXP + pos];
                            float gv = accg[m][n][r];
                            float uv = accu[m][n][r];
                            float hv = (gv / (1.f + __expf(-gv))) * uv * p;
                            hout[(size_t)(hbase + pos) * INTERD + col] = __float2bfloat16(hv);
                        }
                    }
        }
    }
}

// ======================= GEMM2: out2[slot] = h[slot] @ wd[e]^T (bf16) =================
// R14 structure (session best): tile 128slot x 256col, BK=32, 44 K-tiles,
// 8 waves (2M x 4N), wave 64x64. 3-slot ring (72KB), prefetch 2, vmcnt(6), swizzle.
// Static grid: bx = e + 8*(mt + 8*nt), mt<8, nt<4 -> 256 blocks. out2 in bf16.
__global__ __launch_bounds__(512, 4) void gemm2_kernel(const bf16* __restrict__ h,
                                                       const bf16* __restrict__ wdb,
                                                       bf16* __restrict__ out2,
                                                       const int* __restrict__ counts,
                                                       const int* __restrict__ offsets) {
    int bx = blockIdx.x;
    int e  = bx & 7;
    int mt = (bx >> 3) & 7;
    int nt = bx >> 6;                 // 0..3
    int cnt = counts[e];
    int n0 = nt * 256;
    int hbase = offsets[e];

    __shared__ __align__(16) bf16 smem[3 * 12288];

    int tid  = threadIdx.x;
    int lane = tid & 63;
    int wid  = tid >> 6;
    int wm   = wid >> 2;              // 0..1 (64-slot stripe)
    int wn   = wid & 3;               // 0..3 (64-col stripe)

    int srow = tid >> 2;                              // 0..127
    int qs   = (((tid & 3) ^ ((srow >> 1) & 3)) * 8);
    int l15  = lane & 15;
    int l4   = lane >> 4;

    int offA[4], offB[4];
#pragma unroll
    for (int m = 0; m < 4; m++) {
        int r = wm * 64 + m * 16 + l15;
        offA[m] = r * 32 + ((l4 ^ ((r >> 1) & 3)) * 8);
    }
#pragma unroll
    for (int n = 0; n < 4; n++) {
        int r = wn * 64 + n * 16 + l15;               // 0..255
        offB[n] = 4096 + r * 32 + ((l4 ^ ((r >> 1) & 3)) * 8);
    }

    const bf16* gB0 = wdb + ((size_t)e * EDIM + n0 + srow) * INTERD + qs;
    const bf16* gB1 = wdb + ((size_t)e * EDIM + n0 + 128 + srow) * INTERD + qs;

    for (int m0 = mt * 128; m0 < cnt; m0 += 1024) {
        WAIT_VM(0);
        const bf16* gA = h + (size_t)(hbase + min(m0 + srow, cnt - 1)) * INTERD + qs;

        f32x4 acc[4][4];
#pragma unroll
        for (int m = 0; m < 4; m++)
#pragma unroll
            for (int n = 0; n < 4; n++) acc[m][n] = (f32x4){0.f, 0.f, 0.f, 0.f};

#define SB2(t) (smem + ((t) % 3) * 12288)
#define G2_STAGE(t) do { bf16* sb_ = SB2(t); int ko_ = (t) * 32; \
        GL16(gA + ko_,  sb_ + wid * 512); \
        GL16(gB0 + ko_, sb_ + 4096 + wid * 512); \
        GL16(gB1 + ko_, sb_ + 8192 + wid * 512); } while (0)

        G2_STAGE(0); G2_STAGE(1);

        for (int t = 0; t < 44; ++t) {
            if (t < 42)       { G2_STAGE(t + 2); WAIT_VM(6); }
            else if (t == 42) { WAIT_VM(3); }
            else              { WAIT_VM(0); }
            BAR();
            const bf16* sb = SB2(t);
            short8 a_[4], b_[4];
#pragma unroll
            for (int m = 0; m < 4; m++) a_[m] = *(const short8*)&sb[offA[m]];
#pragma unroll
            for (int n = 0; n < 4; n++) b_[n] = *(const short8*)&sb[offB[n]];
            PRIO(1);
#pragma unroll
            for (int m = 0; m < 4; m++)
#pragma unroll
                for (int n = 0; n < 4; n++)
                    acc[m][n] = __builtin_amdgcn_mfma_f32_16x16x32_bf16(a_[m], b_[n], acc[m][n], 0, 0, 0);
            PRIO(0);
            BAR();
        }
#undef SB2
#undef G2_STAGE

#pragma unroll
        for (int m = 0; m < 4; m++)
#pragma unroll
            for (int n = 0; n < 4; n++)
#pragma unroll
                for (int r = 0; r < 4; r++) {
                    int pos = m0 + wm * 64 + m * 16 + l4 * 4 + r;
                    if (pos < cnt) {
                        int col = n0 + wn * 64 + n * 16 + l15;
                        out2[(size_t)(hbase + pos) * EDIM + col] = __float2bfloat16(acc[m][n][r]);
                    }
                }
    }
}

// ---------------- combine: y[t] = out2[slot0] + out2[slot1] (probs already folded) ---
__global__ __launch_bounds__(256) void combine_kernel(const bf16* __restrict__ out2,
                                                      const int* __restrict__ inv,
                                                      const int* __restrict__ offsets,
                                                      float* __restrict__ y) {
    int idx = blockIdx.x * 256 + threadIdx.x;   // NTOK*EDIM/8 threads
    int t = idx >> 7;
    int c = (idx & 127) * 8;
    int a = inv[2 * t], b = inv[2 * t + 1];
    const short8 va = *(const short8*)(out2 + (size_t)(offsets[a >> 16] + (a & 0xFFFF)) * EDIM + c);
    const short8 vb = *(const short8*)(out2 + (size_t)(offsets[b >> 16] + (b & 0xFFFF)) * EDIM + c);
    float o[8];
#pragma unroll
    for (int j = 0; j < 8; j++) {
        unsigned ua = ((unsigned)(unsigned short)va[j]) << 16;
        unsigned ub = ((unsigned)(unsigned short)vb[j]) << 16;
        o[j] = *(float*)&ua + *(float*)&ub;
    }
    float* yp = y + (size_t)t * EDIM + c;
    *(float4*)yp       = (float4){o[0], o[1], o[2], o[3]};
    *(float4*)(yp + 4) = (float4){o[4], o[5], o[6], o[7]};
}

// ---------------- launch ----------------
extern "C" void kernel_launch(void* const* d_in, const int* in_sizes, int n_in,
                              void* d_out, int out_size, void* d_ws, size_t ws_size,
                              hipStream_t stream) {
    const float* x      = (const float*)d_in[0];
    const float* gate_w = (const float*)d_in[1];
    const float* wg     = (const float*)d_in[2];
    const float* wu     = (const float*)d_in[3];
    const float* wd     = (const float*)d_in[4];
    float* y = (float*)d_out;

    char* ws = (char*)d_ws;
    constexpr size_t SZ_XB = (size_t)NTOK * EDIM * 2;          // 8 MB
    constexpr size_t SZ_W  = (size_t)WELEM * 2;                // 23.07 MB
    constexpr size_t SZ_H  = (size_t)NTOK * 2 * INTERD * 2;    // 23.07 MB
    bf16* xb  = (bf16*)ws;
    bf16* wgb = (bf16*)(ws + SZ_XB);
    bf16* wub = (bf16*)(ws + SZ_XB + SZ_W);
    bf16* wdb = (bf16*)(ws + SZ_XB + 2 * SZ_W);
    bf16* h   = (bf16*)(ws + SZ_XB + 3 * SZ_W);
    char* meta = ws + SZ_XB + 3 * SZ_W + SZ_H;
    int*   counts  = (int*)meta;
    int*   offsets = (int*)(meta + 256);
    int*   ptok    = (int*)(meta + 512);
    float* pprob   = (float*)(meta + 512 + (size_t)NEXPT * MAXP * 4);
    int*   inv     = (int*)(meta + 512 + (size_t)NEXPT * MAXP * 8);
    char*  meta2   = meta + 512 + (size_t)NEXPT * MAXP * 8 + (size_t)NTOK * 2 * 4;
    int*   wq1     = (int*)meta2;                      // 8 entries, 128B stride
    int*   wq2     = (int*)(meta2 + 1024);             // 8 entries, 128B stride
    int*   sel     = (int*)(meta2 + 2048);
    float* tprob   = (float*)(meta2 + 2048 + (size_t)NTOK * 4);
    // out2 bf16 (8192*1024*2 = 16.8 MB) aliases wgb (23 MB), dead after gemm1
    bf16* out2 = (bf16*)(ws + SZ_XB);

    prep_kernel<<<3072 + NTOK / 4, 256, 0, stream>>>(wg, wgb, wu, wub, wd, wdb,
                                                     x, gate_w, xb, sel, tprob);
    bucket_kernel<<<1, 512, 0, stream>>>(sel, tprob, counts, offsets, ptok, pprob, inv,
                                         wq1, wq2);

    // 512 blocks (2/CU, 72KB LDS); per-expert queue + steal; bx&7 = expert -> XCD
    gemm1_kernel<<<512, 512, 0, stream>>>(
        xb, wgb, wub, h, counts, offsets, ptok, pprob, wq1);
    // 256 blocks (R14 structure, 72KB LDS); bf16 out2
    gemm2_kernel<<<NEXPT * 8 * (EDIM / 256), 512, 0, stream>>>(
        h, wdb, out2, counts, offsets);
    combine_kernel<<<NTOK * EDIM / 8 / 256, 256, 0, stream>>>(out2, inv, offsets, y);
}

// Round 18
// 217.913 us; speedup vs baseline: 1.1862x; 1.0068x over previous
//
#include <hip/hip_runtime.h>
#include <hip/hip_bf16.h>
#include <stdint.h>

typedef __hip_bfloat16 bf16;
typedef __attribute__((ext_vector_type(8))) short short8;
typedef __attribute__((ext_vector_type(4))) float f32x4;

#define NTOK  4096      // B*T
#define EDIM  1024
#define NEXPT 8
#define INTERD 1408
#define MAXP  4096
#define WELEM (NEXPT * INTERD * EDIM)

// async global->LDS, 16B per lane, dest = wave-uniform base + lane*16 (LINEAR)
#define GL16(g, l) __builtin_amdgcn_global_load_lds( \
    (const __attribute__((address_space(1))) unsigned int*)(g), \
    (__attribute__((address_space(3))) unsigned int*)(l), 16, 0, 0)

#define WAIT_VM(n)   asm volatile("s_waitcnt vmcnt(" #n ")" ::: "memory")
#define BAR()        __builtin_amdgcn_s_barrier()
#define PRIO(n)      __builtin_amdgcn_s_setprio(n)

// ---- prep: fused {wg,wu,wd -> bf16} + {router top2 + probs + x->bf16}. NO ATOMICS. --
__global__ __launch_bounds__(256) void prep_kernel(const float* __restrict__ wg, bf16* __restrict__ wgb,
                                                   const float* __restrict__ wu, bf16* __restrict__ wub,
                                                   const float* __restrict__ wd, bf16* __restrict__ wdb,
                                                   const float* __restrict__ x,
                                                   const float* __restrict__ gw,
                                                   bf16* __restrict__ xb,
                                                   int* __restrict__ sel,
                                                   float* __restrict__ tprob) {
    int b = blockIdx.x;
    if (b < 3072) {
        const float* src; bf16* dst;
        if (b < 1024)      { src = wg; dst = wgb; }
        else if (b < 2048) { src = wu; dst = wub; b -= 1024; }
        else               { src = wd; dst = wdb; b -= 2048; }
        int i = (b * 256 + threadIdx.x) * 4;
        int stride = 1024 * 256 * 4;
        for (; i < WELEM; i += stride) {
            float4 v = *(const float4*)(src + i);
            ushort4 o; bf16 t;
            t = __float2bfloat16(v.x); o.x = *(unsigned short*)&t;
            t = __float2bfloat16(v.y); o.y = *(unsigned short*)&t;
            t = __float2bfloat16(v.z); o.z = *(unsigned short*)&t;
            t = __float2bfloat16(v.w); o.w = *(unsigned short*)&t;
            *(ushort4*)(dst + i) = o;
        }
        return;
    }
    // ---- router: one token per wave, fp64-exact scores ----
    int t = (b - 3072) * 4 + (threadIdx.x >> 6);
    int lane = threadIdx.x & 63;
    const float* xr = x + (size_t)t * EDIM;
    float xv[16];
#pragma unroll
    for (int j = 0; j < 4; j++) {
        float4 v = *(const float4*)(xr + lane * 16 + j * 4);
        xv[4 * j] = v.x; xv[4 * j + 1] = v.y; xv[4 * j + 2] = v.z; xv[4 * j + 3] = v.w;
    }
    bf16* xbr = xb + (size_t)t * EDIM;
#pragma unroll
    for (int j = 0; j < 4; j++) {
        ushort4 o; bf16 c;
        c = __float2bfloat16(xv[4 * j]);     o.x = *(unsigned short*)&c;
        c = __float2bfloat16(xv[4 * j + 1]); o.y = *(unsigned short*)&c;
        c = __float2bfloat16(xv[4 * j + 2]); o.z = *(unsigned short*)&c;
        c = __float2bfloat16(xv[4 * j + 3]); o.w = *(unsigned short*)&c;
        *(ushort4*)(xbr + lane * 16 + j * 4) = o;
    }
    double acc[NEXPT];
#pragma unroll
    for (int e = 0; e < NEXPT; e++) acc[e] = 0.0;
#pragma unroll
    for (int e = 0; e < NEXPT; e++) {
        const float* gr = gw + e * EDIM + lane * 16;
#pragma unroll
        for (int j = 0; j < 16; j++) acc[e] += (double)xv[j] * (double)gr[j];
    }
#pragma unroll
    for (int off = 32; off >= 1; off >>= 1) {
#pragma unroll
        for (int e = 0; e < NEXPT; e++) acc[e] += __shfl_xor(acc[e], off, 64);
    }
    if (lane == 0) {
        int e0 = 0; double s0 = acc[0];
        for (int e = 1; e < NEXPT; e++) if (acc[e] > s0) { s0 = acc[e]; e0 = e; }
        int e1 = -1; double s1 = -1e300;
        for (int e = 0; e < NEXPT; e++) if (e != e0 && acc[e] > s1) { s1 = acc[e]; e1 = e; }
        float z = __expf((float)(s1 - s0));
        float p0 = 1.f / (1.f + z);
        sel[t] = e0 | (e1 << 8);
        tprob[2 * t] = p0;
        tprob[2 * t + 1] = 1.f - p0;
    }
}

// ------- bucket: stable counting-sort of (token,slot) into expert buckets ----------
__global__ __launch_bounds__(512) void bucket_kernel(const int* __restrict__ sel,
                                                     const float* __restrict__ tprob,
                                                     int* __restrict__ counts,
                                                     int* __restrict__ offsets,
                                                     int* __restrict__ ptok,
                                                     float* __restrict__ pprob,
                                                     int* __restrict__ inv,
                                                     int* __restrict__ wq1,
                                                     int* __restrict__ wq2) {
    __shared__ int scnt[NEXPT];
    int w = threadIdx.x >> 6;
    int lane = threadIdx.x & 63;
    unsigned long long ltmask = (lane == 63) ? ~0ull >> 1 : (1ull << lane) - 1;
    int base = 0;
    for (int t0 = 0; t0 < NTOK; t0 += 64) {
        int t = t0 + lane;
        int s = sel[t];
        int e0 = s & 0xff, e1 = (s >> 8) & 0xff;
        unsigned long long m0 = __ballot(e0 == w);
        if (e0 == w) {
            int pos = base + __popcll(m0 & ltmask);
            ptok[w * MAXP + pos] = t;
            pprob[w * MAXP + pos] = tprob[2 * t];
            inv[2 * t] = (w << 16) | pos;
        }
        base += __popcll(m0);
        unsigned long long m1 = __ballot(e1 == w);
        if (e1 == w) {
            int pos = base + __popcll(m1 & ltmask);
            ptok[w * MAXP + pos] = t;
            pprob[w * MAXP + pos] = tprob[2 * t + 1];
            inv[2 * t + 1] = (w << 16) | pos;
        }
        base += __popcll(m1);
    }
    if (lane == 0) scnt[w] = base;
    __syncthreads();
    if (threadIdx.x < NEXPT) {
        int off = 0;
        for (int e = 0; e < (int)threadIdx.x; e++) off += scnt[e];
        counts[threadIdx.x] = scnt[threadIdx.x];
        offsets[threadIdx.x] = off;
        wq1[threadIdx.x * 32] = 0;    // 128B-padded queue heads
        wq2[threadIdx.x * 32] = 0;
    }
}

// ======================= GEMM1: h = p * silu(x@wg^T) * (x@wu^T) =======================
// Tile 128tok x 128inter, BK=32, 32 K-tiles. 8 waves (2M x 4N), wave 64x32 on g AND u.
// 3-slot LDS ring (72KB) -> 2 blocks/CU. Prefetch 2, counted vmcnt(6), XOR swizzle.
// (512,4): no spills. Padded per-expert queue + stealing; bx&7 = expert -> XCD.
__global__ __launch_bounds__(512, 4) void gemm1_kernel(const bf16* __restrict__ xb,
                                                       const bf16* __restrict__ wgb,
                                                       const bf16* __restrict__ wub,
                                                       bf16* __restrict__ hout,
                                                       const int* __restrict__ counts,
                                                       const int* __restrict__ offsets,
                                                       const int* __restrict__ ptok,
                                                       const float* __restrict__ pprob,
                                                       int* __restrict__ wq1) {
    int eown = blockIdx.x & 7;

    __shared__ __align__(16) bf16 smem[3 * 12288];
    __shared__ int s_wi;

    int tid  = threadIdx.x;
    int lane = tid & 63;
    int wid  = tid >> 6;
    int wm   = wid >> 2;              // 0..1  (64-tok stripe)
    int wn   = wid & 3;               // 0..3  (32-inter stripe)

    int srow = tid >> 2;                              // staging row 0..127
    int qs   = (((tid & 3) ^ ((srow >> 1) & 3)) * 8); // swizzled SOURCE chunk (elems)
    int l15  = lane & 15;
    int l4   = lane >> 4;                             // 0..3 (K-chunk)

    int offA[4], offG[2];
#pragma unroll
    for (int m = 0; m < 4; m++) {
        int r = wm * 64 + m * 16 + l15;
        offA[m] = r * 32 + ((l4 ^ ((r >> 1) & 3)) * 8);
    }
#pragma unroll
    for (int n = 0; n < 2; n++) {
        int r = wn * 32 + n * 16 + l15;
        offG[n] = r * 32 + ((l4 ^ ((r >> 1) & 3)) * 8);
    }

    for (int ei = 0; ei < NEXPT; ++ei) {
        int e = (eown + ei) & 7;      // own expert first, then steal
        int cnt = counts[e];
        int mtiles = (cnt + 127) >> 7;
        int tiles = mtiles * (INTERD / 128);
        int hbase = offsets[e];

        for (;;) {
            if (tid == 0) s_wi = atomicAdd(&wq1[e * 32], 1);
            __syncthreads();
            int wi = s_wi;
            __syncthreads();
            if (wi >= tiles) break;
            int mt = wi % mtiles;     // mt-fastest: concurrent blocks share G/U panel
            int nt = wi / mtiles;
            int m0 = mt * 128;
            int n0 = nt * 128;

            WAIT_VM(0);               // clean vmcnt (prior stores drained)
            const bf16* gA = xb + (size_t)ptok[e * MAXP + min(m0 + srow, cnt - 1)] * EDIM + qs;
            const bf16* gG = wgb + ((size_t)e * INTERD + n0 + srow) * EDIM + qs;
            const bf16* gU = wub + ((size_t)e * INTERD + n0 + srow) * EDIM + qs;

            f32x4 accg[4][2], accu[4][2];
#pragma unroll
            for (int m = 0; m < 4; m++)
#pragma unroll
                for (int n = 0; n < 2; n++) {
                    accg[m][n] = (f32x4){0.f, 0.f, 0.f, 0.f};
                    accu[m][n] = (f32x4){0.f, 0.f, 0.f, 0.f};
                }

#define SB1(t) (smem + ((t) % 3) * 12288)
#define G1_STAGE(t) do { bf16* sb_ = SB1(t); int ko_ = (t) * 32; \
            GL16(gA + ko_, sb_ + wid * 512); \
            GL16(gG + ko_, sb_ + 4096 + wid * 512); \
            GL16(gU + ko_, sb_ + 8192 + wid * 512); } while (0)

            G1_STAGE(0); G1_STAGE(1);     // 6 loads in flight

            for (int t = 0; t < 32; ++t) {
                if (t < 30)       { G1_STAGE(t + 2); WAIT_VM(6); }  // tile t landed
                else if (t == 30) { WAIT_VM(3); }
                else              { WAIT_VM(0); }
                BAR();
                const bf16* sb = SB1(t);
                short8 a_[4], gf[2], uf[2];
#pragma unroll
                for (int m = 0; m < 4; m++) a_[m] = *(const short8*)&sb[offA[m]];
#pragma unroll
                for (int n = 0; n < 2; n++) {
                    gf[n] = *(const short8*)&sb[4096 + offG[n]];
                    uf[n] = *(const short8*)&sb[8192 + offG[n]];
                }
                PRIO(1);
#pragma unroll
                for (int m = 0; m < 4; m++)
#pragma unroll
                    for (int n = 0; n < 2; n++) {
                        accg[m][n] = __builtin_amdgcn_mfma_f32_16x16x32_bf16(a_[m], gf[n], accg[m][n], 0, 0, 0);
                        accu[m][n] = __builtin_amdgcn_mfma_f32_16x16x32_bf16(a_[m], uf[n], accu[m][n], 0, 0, 0);
                    }
                PRIO(0);
                BAR();
            }
#undef SB1
#undef G1_STAGE

            // epilogue: h = silu(g) * u * p
#pragma unroll
            for (int m = 0; m < 4; m++)
#pragma unroll
                for (int n = 0; n < 2; n++)
#pragma unroll
                    for (int r = 0; r < 4; r++) {
                        int pos = m0 + wm * 64 + m * 16 + l4 * 4 + r;
                        if (pos < cnt) {
                            int col = n0 + wn * 32 + n * 16 + l15;
                            float p = pprob[e * MAXP + pos];
                            float gv = accg[m][n][r];
                            float uv = accu[m][n][r];
                            float hv = (gv / (1.f + __expf(-gv))) * uv * p;
                            hout[(size_t)(hbase + pos) * INTERD + col] = __float2bfloat16(hv);
                        }
                    }
        }
    }
}

// ======================= GEMM2: out2[slot] = h[slot] @ wd[e]^T (bf16) =================
// R14 structure (session best): tile 128slot x 256col, BK=32, 44 K-tiles,
// 8 waves (2M x 4N), wave 64x64. 3-slot ring (72KB), prefetch 2, vmcnt(6), swizzle.
// Static grid: bx = e + 8*(mt + 8*nt), mt<8, nt<4 -> 256 blocks. out2 in bf16.
__global__ __launch_bounds__(512, 4) void gemm2_kernel(const bf16* __restrict__ h,
                                                       const bf16* __restrict__ wdb,
                                                       bf16* __restrict__ out2,
                                                       const int* __restrict__ counts,
                                                       const int* __restrict__ offsets) {
    int bx = blockIdx.x;
    int e  = bx & 7;
    int mt = (bx >> 3) & 7;
    int nt = bx >> 6;                 // 0..3
    int cnt = counts[e];
    int n0 = nt * 256;
    int hbase = offsets[e];

    __shared__ __align__(16) bf16 smem[3 * 12288];

    int tid  = threadIdx.x;
    int lane = tid & 63;
    int wid  = tid >> 6;
    int wm   = wid >> 2;              // 0..1 (64-slot stripe)
    int wn   = wid & 3;               // 0..3 (64-col stripe)

    int srow = tid >> 2;                              // 0..127
    int qs   = (((tid & 3) ^ ((srow >> 1) & 3)) * 8);
    int l15  = lane & 15;
    int l4   = lane >> 4;

    int offA[4], offB[4];
#pragma unroll
    for (int m = 0; m < 4; m++) {
        int r = wm * 64 + m * 16 + l15;
        offA[m] = r * 32 + ((l4 ^ ((r >> 1) & 3)) * 8);
    }
#pragma unroll
    for (int n = 0; n < 4; n++) {
        int r = wn * 64 + n * 16 + l15;               // 0..255
        offB[n] = 4096 + r * 32 + ((l4 ^ ((r >> 1) & 3)) * 8);
    }

    const bf16* gB0 = wdb + ((size_t)e * EDIM + n0 + srow) * INTERD + qs;
    const bf16* gB1 = wdb + ((size_t)e * EDIM + n0 + 128 + srow) * INTERD + qs;

    for (int m0 = mt * 128; m0 < cnt; m0 += 1024) {
        WAIT_VM(0);
        const bf16* gA = h + (size_t)(hbase + min(m0 + srow, cnt - 1)) * INTERD + qs;

        f32x4 acc[4][4];
#pragma unroll
        for (int m = 0; m < 4; m++)
#pragma unroll
            for (int n = 0; n < 4; n++) acc[m][n] = (f32x4){0.f, 0.f, 0.f, 0.f};

#define SB2(t) (smem + ((t) % 3) * 12288)
#define G2_STAGE(t) do { bf16* sb_ = SB2(t); int ko_ = (t) * 32; \
        GL16(gA + ko_,  sb_ + wid * 512); \
        GL16(gB0 + ko_, sb_ + 4096 + wid * 512); \
        GL16(gB1 + ko_, sb_ + 8192 + wid * 512); } while (0)

        G2_STAGE(0); G2_STAGE(1);

        for (int t = 0; t < 44; ++t) {
            if (t < 42)       { G2_STAGE(t + 2); WAIT_VM(6); }
            else if (t == 42) { WAIT_VM(3); }
            else              { WAIT_VM(0); }
            BAR();
            const bf16* sb = SB2(t);
            short8 a_[4], b_[4];
#pragma unroll
            for (int m = 0; m < 4; m++) a_[m] = *(const short8*)&sb[offA[m]];
#pragma unroll
            for (int n = 0; n < 4; n++) b_[n] = *(const short8*)&sb[offB[n]];
            PRIO(1);
#pragma unroll
            for (int m = 0; m < 4; m++)
#pragma unroll
                for (int n = 0; n < 4; n++)
                    acc[m][n] = __builtin_amdgcn_mfma_f32_16x16x32_bf16(a_[m], b_[n], acc[m][n], 0, 0, 0);
            PRIO(0);
            BAR();
        }
#undef SB2
#undef G2_STAGE

#pragma unroll
        for (int m = 0; m < 4; m++)
#pragma unroll
            for (int n = 0; n < 4; n++)
#pragma unroll
                for (int r = 0; r < 4; r++) {
                    int pos = m0 + wm * 64 + m * 16 + l4 * 4 + r;
                    if (pos < cnt) {
                        int col = n0 + wn * 64 + n * 16 + l15;
                        out2[(size_t)(hbase + pos) * EDIM + col] = __float2bfloat16(acc[m][n][r]);
                    }
                }
    }
}

// ---------------- combine: y[t] = out2[slot0] + out2[slot1] (probs already folded) ---
__global__ __launch_bounds__(256) void combine_kernel(const bf16* __restrict__ out2,
                                                      const int* __restrict__ inv,
                                                      const int* __restrict__ offsets,
                                                      float* __restrict__ y) {
    int idx = blockIdx.x * 256 + threadIdx.x;   // NTOK*EDIM/8 threads
    int t = idx >> 7;
    int c = (idx & 127) * 8;
    int a = inv[2 * t], b = inv[2 * t + 1];
    const short8 va = *(const short8*)(out2 + (size_t)(offsets[a >> 16] + (a & 0xFFFF)) * EDIM + c);
    const short8 vb = *(const short8*)(out2 + (size_t)(offsets[b >> 16] + (b & 0xFFFF)) * EDIM + c);
    float o[8];
#pragma unroll
    for (int j = 0; j < 8; j++) {
        unsigned ua = ((unsigned)(unsigned short)va[j]) << 16;
        unsigned ub = ((unsigned)(unsigned short)vb[j]) << 16;
        o[j] = *(float*)&ua + *(float*)&ub;
    }
    float* yp = y + (size_t)t * EDIM + c;
    *(float4*)yp       = (float4){o[0], o[1], o[2], o[3]};
    *(float4*)(yp + 4) = (float4){o[4], o[5], o[6], o[7]};
}

// ---------------- launch ----------------
extern "C" void kernel_launch(void* const* d_in, const int* in_sizes, int n_in,
                              void* d_out, int out_size, void* d_ws, size_t ws_size,
                              hipStream_t stream) {
    const float* x      = (const float*)d_in[0];
    const float* gate_w = (const float*)d_in[1];
    const float* wg     = (const float*)d_in[2];
    const float* wu     = (const float*)d_in[3];
    const float* wd     = (const float*)d_in[4];
    float* y = (float*)d_out;

    char* ws = (char*)d_ws;
    constexpr size_t SZ_XB = (size_t)NTOK * EDIM * 2;          // 8 MB
    constexpr size_t SZ_W  = (size_t)WELEM * 2;                // 23.07 MB
    constexpr size_t SZ_H  = (size_t)NTOK * 2 * INTERD * 2;    // 23.07 MB
    bf16* xb  = (bf16*)ws;
    bf16* wgb = (bf16*)(ws + SZ_XB);
    bf16* wub = (bf16*)(ws + SZ_XB + SZ_W);
    bf16* wdb = (bf16*)(ws + SZ_XB + 2 * SZ_W);
    bf16* h   = (bf16*)(ws + SZ_XB + 3 * SZ_W);
    char* meta = ws + SZ_XB + 3 * SZ_W + SZ_H;
    int*   counts  = (int*)meta;
    int*   offsets = (int*)(meta + 256);
    int*   ptok    = (int*)(meta + 512);
    float* pprob   = (float*)(meta + 512 + (size_t)NEXPT * MAXP * 4);
    int*   inv     = (int*)(meta + 512 + (size_t)NEXPT * MAXP * 8);
    char*  meta2   = meta + 512 + (size_t)NEXPT * MAXP * 8 + (size_t)NTOK * 2 * 4;
    int*   wq1     = (int*)meta2;                      // 8 entries, 128B stride
    int*   wq2     = (int*)(meta2 + 1024);             // 8 entries, 128B stride
    int*   sel     = (int*)(meta2 + 2048);
    float* tprob   = (float*)(meta2 + 2048 + (size_t)NTOK * 4);
    // out2 bf16 (8192*1024*2 = 16.8 MB) aliases wgb (23 MB), dead after gemm1
    bf16* out2 = (bf16*)(ws + SZ_XB);

    prep_kernel<<<3072 + NTOK / 4, 256, 0, stream>>>(wg, wgb, wu, wub, wd, wdb,
                                                     x, gate_w, xb, sel, tprob);
    bucket_kernel<<<1, 512, 0, stream>>>(sel, tprob, counts, offsets, ptok, pprob, inv,
                                         wq1, wq2);

    // 512 blocks (2/CU, 72KB LDS); per-expert queue + steal; bx&7 = expert -> XCD
    gemm1_kernel<<<512, 512, 0, stream>>>(
        xb, wgb, wub, h, counts, offsets, ptok, pprob, wq1);
    // 256 blocks (R14 structure, 72KB LDS); bf16 out2
    gemm2_kernel<<<NEXPT * 8 * (EDIM / 256), 512, 0, stream>>>(
        h, wdb, out2, counts, offsets);
    combine_kernel<<<NTOK * EDIM / 8 / 256, 256, 0, stream>>>(out2, inv, offsets, y);
}